// Round 4
// baseline (107.106 us; speedup 1.0000x reference)
//
#include <hip/hip_runtime.h>
#include <math.h>

#define BATCH_N 884736    // 96*96*96
#define NTOT   1769472    // 2*BATCH_N
#define NCHUNKW 18        // chunks per wave: 13824 / 768
#define GBLK 384          // k_gemm blocks per batch (2 waves each)
#define GWAVES 768        // waves per batch: exactly 3 blocks/CU over 2 batches
#define KBLK 512          // k_minmax blocks
#define QS 190.0f         // weight quantization scale (max w=2/3 -> 127)

// voxel-major tile: 6 bin-blocks x (64 vox x 16 bins) bytes; padded bin = bin+16
// so real bins 0..63 occupy blocks 1..4 exactly; blocks 0 and 5 absorb edges.
#define BBLK_B 1024
#define TILE_B 6144       // per matrix
#define WAVE_B 12288      // A+B per wave
#define MROW 66           // merge region row stride (floats)

// ws layout (bytes):
//   ghist  at   256 : float[2][4096]   (zeroed by k_minmax; atomic-accumulated by k_gemm)
//   kblk   at 36864 : uint4[512]       (plain-stored by k_minmax)
#define OFF_GHIST 256
#define OFF_KBLK 36864

typedef int v4i __attribute__((ext_vector_type(4)));
typedef int v2i __attribute__((ext_vector_type(2)));

// monotone float->uint key: max over keys == max over floats
__device__ __forceinline__ unsigned fkey(float x){
    unsigned u = __float_as_uint(x);
    return (u & 0x80000000u) ? ~u : (u | 0x80000000u);
}
__device__ __forceinline__ float fdecode(unsigned k){
    return __uint_as_float((k & 0x80000000u) ? (k ^ 0x80000000u) : ~k);
}

// cubic B-spline weights for bins it0-1..it0+2, u = frac(v) in [0,1)
__device__ __forceinline__ void bw4(float u, float w[4]){
    float um = 1.f - u;
    float u2 = u*u, um2 = um*um;
    w[0] = um2*um*(1.f/6.f);
    w[3] = u2*u*(1.f/6.f);
    w[1] = 0.6666666666666667f - u2 + 0.5f*u2*u;
    w[2] = 0.6666666666666667f - um2 + 0.5f*um2*um;
}

// per-block min/max -> plain store into kblk[block]; blocks 0..7 also zero ghist
__global__ void __launch_bounds__(256)
k_minmax(const float4* __restrict__ t4, const float4* __restrict__ s4,
         int n4, uint4* __restrict__ kblk, float* __restrict__ ghist){
    __shared__ unsigned red[4][4];   // [wave][key]

    if (blockIdx.x < 8){
        ghist[blockIdx.x*1024 + threadIdx.x] = 0.f;
        ghist[blockIdx.x*1024 + 256 + threadIdx.x] = 0.f;
        ghist[blockIdx.x*1024 + 512 + threadIdx.x] = 0.f;
        ghist[blockIdx.x*1024 + 768 + threadIdx.x] = 0.f;
    }

    unsigned mt=0u, mnt=0u, ms=0u, mns=0u;
    int stride = gridDim.x * blockDim.x;
    for (int i = blockIdx.x*blockDim.x + threadIdx.x; i < n4; i += stride){
        float4 a = t4[i];
        float4 b = s4[i];
        mt  = max(mt,  max(max(fkey(a.x),  fkey(a.y)),  max(fkey(a.z),  fkey(a.w))));
        mnt = max(mnt, max(max(fkey(-a.x), fkey(-a.y)), max(fkey(-a.z), fkey(-a.w))));
        ms  = max(ms,  max(max(fkey(b.x),  fkey(b.y)),  max(fkey(b.z),  fkey(b.w))));
        mns = max(mns, max(max(fkey(-b.x), fkey(-b.y)), max(fkey(-b.z), fkey(-b.w))));
    }
    #pragma unroll
    for (int off = 32; off; off >>= 1){
        mt  = max(mt,  __shfl_down(mt,  off));
        mnt = max(mnt, __shfl_down(mnt, off));
        ms  = max(ms,  __shfl_down(ms,  off));
        mns = max(mns, __shfl_down(mns, off));
    }
    int wid = threadIdx.x >> 6;
    if ((threadIdx.x & 63) == 0){
        red[wid][0] = mt; red[wid][1] = mnt; red[wid][2] = ms; red[wid][3] = mns;
    }
    __syncthreads();
    if (threadIdx.x == 0){
        uint4 q;
        q.x = max(max(red[0][0], red[1][0]), max(red[2][0], red[3][0]));
        q.y = max(max(red[0][1], red[1][1]), max(red[2][1], red[3][1]));
        q.z = max(max(red[0][2], red[1][2]), max(red[2][2], red[3][2]));
        q.w = max(max(red[0][3], red[1][3]), max(red[2][3], red[3][3]));
        kblk[blockIdx.x] = q;
    }
}

// joint histogram as tall-skinny GEMM on int8.
// Voxel-major LDS tiles: scatter = 2 aligned ds_write_b128 per matrix (weights
// are 4 contiguous bytes in the voxel's own 16B row; spill row handles
// bin-block straddle). Fragments via ds_read_b64_tr_b8 hardware transpose
// (lane gets bin-column, rows = voxels). K-order is a permutation of voxels,
// identical for A and B -> MFMA result unchanged.
__global__ void __launch_bounds__(128, 3)
k_gemm(const float* __restrict__ t, const float* __restrict__ s,
       const uint4* __restrict__ kblk, float* __restrict__ ghist){
    __shared__ __align__(1024) int4 smem4[2*WAVE_B/16];   // 24576 B
    __shared__ unsigned kred[2][4];

    int tid = threadIdx.x;
    int lane = tid & 63;
    int warp = tid >> 6;
    int rrow = lane & 15;                  // fragment row/col within 16-tile
    int kgrp = lane >> 4;                  // C/D row group
    int b = blockIdx.y;

    char* As = (char*)smem4 + warp*WAVE_B; // this wave's tiles
    char* Bs = As + TILE_B;

    // zero tiles (wave-private: no barrier needed). 768 int4 = 12 per lane.
    {
        int4* wz = (int4*)As;
        int4 z4 = {0,0,0,0};
        #pragma unroll
        for (int i = 0; i < 12; ++i)
            wz[i*64 + lane] = z4;
    }

    // reduce the 512 per-block key quads (redundant per block; ~L2-hit)
    {
        unsigned m0=0u, m1=0u, m2=0u, m3=0u;
        #pragma unroll
        for (int i = 0; i < 4; ++i){
            uint4 q = kblk[tid + i*128];
            m0 = max(m0, q.x); m1 = max(m1, q.y);
            m2 = max(m2, q.z); m3 = max(m3, q.w);
        }
        #pragma unroll
        for (int off = 32; off; off >>= 1){
            m0 = max(m0, __shfl_down(m0, off));
            m1 = max(m1, __shfl_down(m1, off));
            m2 = max(m2, __shfl_down(m2, off));
            m3 = max(m3, __shfl_down(m3, off));
        }
        if (lane == 0){
            kred[warp][0] = m0; kred[warp][1] = m1;
            kred[warp][2] = m2; kred[warp][3] = m3;
        }
        __syncthreads();
    }
    float tmax =  fdecode(max(kred[0][0], kred[1][0]));
    float tmin = -fdecode(max(kred[0][1], kred[1][1]));
    float smax =  fdecode(max(kred[0][2], kred[1][2]));
    float smin = -fdecode(max(kred[0][3], kred[1][3]));
    float tsc = 64.f / (tmax - tmin);
    float ssc = 64.f / (smax - smin);

    const float* tb = t + (size_t)b*BATCH_N;
    const float* sb = s + (size_t)b*BATCH_N;

    v4i acc[4][4];
    #pragma unroll
    for (int i = 0; i < 4; ++i)
        #pragma unroll
        for (int j = 0; j < 4; ++j)
            acc[i][j] = (v4i){0,0,0,0};

    int c0 = blockIdx.x*2 + warp;          // wave index within batch [0, 768)
    int vrow = ((lane >> 3) << 7) + ((lane & 7) << 4);  // (vox/8)*128 + (vox%8)*16
    unsigned abase = (unsigned)(unsigned long long)As;  // LDS byte offset
    unsigned bbase = (unsigned)(unsigned long long)Bs;

    // depth-2 prefetch pipeline
    float tq0 = tb[(size_t)c0*64 + lane];
    float sq0 = sb[(size_t)c0*64 + lane];
    float tq1 = tb[(size_t)(c0 + GWAVES)*64 + lane];
    float sq1 = sb[(size_t)(c0 + GWAVES)*64 + lane];

    for (int it = 0; it < NCHUNKW; ++it){
        // issue prefetch for chunk it+2 (clamped to a safe in-range address)
        int cpre = c0 + (it < NCHUNKW-2 ? (it + 2)*GWAVES : 0);
        float tnn = tb[(size_t)cpre*64 + lane];
        float snn = sb[(size_t)cpre*64 + lane];

        // ---- A: weights, pack, position into 128-bit row (+spill) ----
        float vt = (tq0 - tmin) * tsc;     // in [0,64]
        int it0 = (int)vt;
        float wt[4]; bw4(vt - (float)it0, wt);
        unsigned Wa = (unsigned)__float2int_rn(wt[0]*QS)
                    | ((unsigned)__float2int_rn(wt[1]*QS) << 8)
                    | ((unsigned)__float2int_rn(wt[2]*QS) << 16)
                    | ((unsigned)__float2int_rn(wt[3]*QS) << 24);
        int ca = it0 + 15;                 // padded col of first weight (bin-1+16)
        int ga = ca >> 4, sha = (ca & 15) << 3;
        unsigned long long Wa64 = Wa;
        unsigned long long alo = (sha < 64) ? (Wa64 << sha) : 0ull;
        unsigned long long ahi = (sha < 64) ? (sha ? (Wa64 >> (64 - sha)) : 0ull)
                                            : (Wa64 << (sha - 64));
        unsigned long long asp = (sha > 96) ? (Wa64 >> (128 - sha)) : 0ull;

        // ---- B: same ----
        float vs = (sq0 - smin) * ssc;
        int is0 = (int)vs;
        float wsv[4]; bw4(vs - (float)is0, wsv);
        unsigned Wb = (unsigned)__float2int_rn(wsv[0]*QS)
                    | ((unsigned)__float2int_rn(wsv[1]*QS) << 8)
                    | ((unsigned)__float2int_rn(wsv[2]*QS) << 16)
                    | ((unsigned)__float2int_rn(wsv[3]*QS) << 24);
        int cb = is0 + 15;
        int gb = cb >> 4, shb = (cb & 15) << 3;
        unsigned long long Wb64 = Wb;
        unsigned long long blo = (shb < 64) ? (Wb64 << shb) : 0ull;
        unsigned long long bhi = (shb < 64) ? (shb ? (Wb64 >> (64 - shb)) : 0ull)
                                            : (Wb64 << (shb - 64));
        unsigned long long bsp = (shb > 96) ? (Wb64 >> (128 - shb)) : 0ull;

        // scatter: voxel-owned 16B rows -> bank-balanced b128 writes
        char* pa = As + ga*BBLK_B + vrow;
        char* pb = Bs + gb*BBLK_B + vrow;
        *(v4i*)pa            = (v4i){(int)alo, (int)(alo>>32), (int)ahi, (int)(ahi>>32)};
        *(v4i*)(pa + BBLK_B) = (v4i){(int)asp, (int)(asp>>32), 0, 0};
        *(v4i*)pb            = (v4i){(int)blo, (int)(blo>>32), (int)bhi, (int)(bhi>>32)};
        *(v4i*)(pb + BBLK_B) = (v4i){(int)bsp, (int)(bsp>>32), 0, 0};

        __asm__ volatile("" ::: "memory");   // pin scatters before tr reads

        // hardware-transpose fragment reads: block m+1 = bins m*16..m*16+15,
        // slabs at +0/+512 = voxels 0..31 / 32..63 (K-permuted, same for A/B)
        v2i a00,a01,a10,a11,a20,a21,a30,a31;
        v2i b00,b01,b10,b11,b20,b21,b30,b31;
        asm volatile("ds_read_b64_tr_b8 %0, %1 offset:1024" : "=v"(a00) : "v"(abase));
        asm volatile("ds_read_b64_tr_b8 %0, %1 offset:1536" : "=v"(a01) : "v"(abase));
        asm volatile("ds_read_b64_tr_b8 %0, %1 offset:2048" : "=v"(a10) : "v"(abase));
        asm volatile("ds_read_b64_tr_b8 %0, %1 offset:2560" : "=v"(a11) : "v"(abase));
        asm volatile("ds_read_b64_tr_b8 %0, %1 offset:3072" : "=v"(a20) : "v"(abase));
        asm volatile("ds_read_b64_tr_b8 %0, %1 offset:3584" : "=v"(a21) : "v"(abase));
        asm volatile("ds_read_b64_tr_b8 %0, %1 offset:4096" : "=v"(a30) : "v"(abase));
        asm volatile("ds_read_b64_tr_b8 %0, %1 offset:4608" : "=v"(a31) : "v"(abase));
        asm volatile("ds_read_b64_tr_b8 %0, %1 offset:1024" : "=v"(b00) : "v"(bbase));
        asm volatile("ds_read_b64_tr_b8 %0, %1 offset:1536" : "=v"(b01) : "v"(bbase));
        asm volatile("ds_read_b64_tr_b8 %0, %1 offset:2048" : "=v"(b10) : "v"(bbase));
        asm volatile("ds_read_b64_tr_b8 %0, %1 offset:2560" : "=v"(b11) : "v"(bbase));
        asm volatile("ds_read_b64_tr_b8 %0, %1 offset:3072" : "=v"(b20) : "v"(bbase));
        asm volatile("ds_read_b64_tr_b8 %0, %1 offset:3584" : "=v"(b21) : "v"(bbase));
        asm volatile("ds_read_b64_tr_b8 %0, %1 offset:4096" : "=v"(b30) : "v"(bbase));
        asm volatile("ds_read_b64_tr_b8 %0, %1 offset:4608" : "=v"(b31) : "v"(bbase));
        asm volatile("s_waitcnt lgkmcnt(0)" ::: "memory");
        __builtin_amdgcn_sched_barrier(0);   // rule #18: stop MFMA hoisting

        v4i af[4], bf[4];
        af[0] = (v4i){a00.x, a00.y, a01.x, a01.y};
        af[1] = (v4i){a10.x, a10.y, a11.x, a11.y};
        af[2] = (v4i){a20.x, a20.y, a21.x, a21.y};
        af[3] = (v4i){a30.x, a30.y, a31.x, a31.y};
        bf[0] = (v4i){b00.x, b00.y, b01.x, b01.y};
        bf[1] = (v4i){b10.x, b10.y, b11.x, b11.y};
        bf[2] = (v4i){b20.x, b20.y, b21.x, b21.y};
        bf[3] = (v4i){b30.x, b30.y, b31.x, b31.y};
        #pragma unroll
        for (int m = 0; m < 4; ++m)
            #pragma unroll
            for (int n = 0; n < 4; ++n)
                acc[m][n] = __builtin_amdgcn_mfma_i32_16x16x64_i8(af[m], bf[n], acc[m][n], 0, 0, 0);

        // zero-restore the two written rows per matrix
        __asm__ volatile("" ::: "memory");
        {
            v4i z = (v4i){0,0,0,0};
            *(v4i*)pa = z; *(v4i*)(pa + BBLK_B) = z;
            *(v4i*)pb = z; *(v4i*)(pb + BBLK_B) = z;
        }

        tq0 = tq1; sq0 = sq1;
        tq1 = tnn; sq1 = snn;
    }

    // merge the two waves' accumulators in LDS (tiles are dead), then
    // global f32 atomic add into ghist (no partials, no reduce kernel).
    const float dq = 1.f / (QS*QS);
    float* fm = (float*)smem4;             // 64*66*4 = 16896 B <= 24576 B
    __syncthreads();
    if (warp == 0){
        #pragma unroll
        for (int m = 0; m < 4; ++m)
            #pragma unroll
            for (int n = 0; n < 4; ++n)
                #pragma unroll
                for (int r = 0; r < 4; ++r)
                    fm[(m*16 + kgrp*4 + r)*MROW + n*16 + rrow] = (float)acc[m][n][r] * dq;
    }
    __syncthreads();
    if (warp == 1){
        #pragma unroll
        for (int m = 0; m < 4; ++m)
            #pragma unroll
            for (int n = 0; n < 4; ++n)
                #pragma unroll
                for (int r = 0; r < 4; ++r)
                    fm[(m*16 + kgrp*4 + r)*MROW + n*16 + rrow] += (float)acc[m][n][r] * dq;
    }
    __syncthreads();
    {
        float* g = ghist + b*4096;
        #pragma unroll
        for (int i = 0; i < 32; ++i){
            int idx = i*128 + tid;
            unsafeAtomicAdd(&g[idx], fm[(idx >> 6)*MROW + (idx & 63)]);
        }
    }
}

__device__ __forceinline__ float blockReduceSum(float v, float* red){
    #pragma unroll
    for (int off = 32; off; off >>= 1) v += __shfl_down(v, off);
    int wid = threadIdx.x >> 6, lane = threadIdx.x & 63;
    __syncthreads();              // protect red[] from previous round
    if (lane == 0) red[wid] = v;
    __syncthreads();
    return red[0] + red[1] + red[2] + red[3];
}

__global__ void k_final(const float* __restrict__ hist, float* __restrict__ out){
    __shared__ float sh[2*4096];
    __shared__ float red[4];
    int tid = threadIdx.x;
    for (int i = tid; i < 8192; i += 256) sh[i] = hist[i];
    __syncthreads();

    float loc = 0.f;
    for (int i = tid; i < 8192; i += 256) loc += sh[i];
    float total = blockReduceSum(loc, red);
    float inv = 1.f / total;

    float nmi[2];
    for (int b = 0; b < 2; ++b){
        const float* h = sh + b*4096;
        float lj = 0.f;
        for (int i = tid; i < 4096; i += 256){
            float p = h[i]*inv;
            lj += p*logf(p + 1e-12f);
        }
        float Hj = -blockReduceSum(lj, red);
        float lt = 0.f;
        if (tid < 64){
            float r = 0.f;
            for (int j = 0; j < 64; ++j) r += h[tid*64 + j];
            float p = r*inv;
            lt = p*logf(p + 1e-12f);
        }
        float Ht = -blockReduceSum(lt, red);
        float ls = 0.f;
        if (tid < 64){
            float c = 0.f;
            for (int j = 0; j < 64; ++j) c += h[j*64 + tid];
            float p = c*inv;
            ls = p*logf(p + 1e-12f);
        }
        float Hs = -blockReduceSum(ls, red);
        nmi[b] = (Ht + Hs) / Hj;
    }
    if (tid == 0) out[0] = -0.5f*(nmi[0] + nmi[1]);
}

extern "C" void kernel_launch(void* const* d_in, const int* in_sizes, int n_in,
                              void* d_out, int out_size, void* d_ws, size_t ws_size,
                              hipStream_t stream) {
    const float* t = (const float*)d_in[0];
    const float* s = (const float*)d_in[1];
    float* out = (float*)d_out;
    float* ghist = (float*)((char*)d_ws + OFF_GHIST);
    uint4* kblk  = (uint4*)((char*)d_ws + OFF_KBLK);

    // no memset node: kblk plain-stored + ghist zeroed by k_minmax; k_gemm
    // atomically accumulates ghist. Kernel boundaries provide visibility.
    k_minmax<<<KBLK, 256, 0, stream>>>((const float4*)t, (const float4*)s, NTOT/4, kblk, ghist);
    k_gemm<<<dim3(GBLK, 2), 128, 0, stream>>>(t, s, kblk, ghist);
    k_final<<<1, 256, 0, stream>>>(ghist, out);
}